// Round 5
// baseline (159.802 us; speedup 1.0000x reference)
//
#include <hip/hip_runtime.h>
#include <hip/hip_bf16.h>
#include <math.h>

#define B_  2
#define NQ  13294
#define NK  13294
#define M_  (B_ * NK)   // 26588

typedef __bf16 bf16x8 __attribute__((ext_vector_type(8)));
typedef float f32x4 __attribute__((ext_vector_type(4)));

static __device__ __forceinline__ f32x4 mfma16(bf16x8 a, bf16x8 b, f32x4 c) {
  return __builtin_amdgcn_mfma_f32_16x16x32_bf16(a, b, c, 0, 0, 0);
}

// ---- pack weights f32 [K=256][N] -> bf16 MFMA B-fragment layout ----
// bf16x8 slot g: lane=g&63, n_sub=(g>>6)&3, kt=(g>>8)&7, bn=g>>11
// n = bn*64 + n_sub*16 + (lane&15),  k = kt*32 + (lane>>4)*8 + j
static __device__ __forceinline__ void pack_one(
    const float* __restrict__ W1, const float* __restrict__ W2,
    int N1, int Ntot, __hip_bfloat16* __restrict__ out, int g) {
  int lane = g & 63;
  int n_sub = (g >> 6) & 3;
  int kt = (g >> 8) & 7;
  int bn = g >> 11;
  int n = bn * 64 + n_sub * 16 + (lane & 15);
  int k0 = kt * 32 + (lane >> 4) * 8;
  const float* src; int nn, Ns;
  if (n < N1) { src = W1; nn = n; Ns = N1; }
  else        { src = W2; nn = n - N1; Ns = Ntot - N1; }
  bf16x8 v;
#pragma unroll
  for (int j = 0; j < 8; ++j) v[j] = (__bf16)src[(size_t)(k0 + j) * Ns + nn];
  *(bf16x8*)(out + (size_t)g * 8) = v;
}

__global__ __launch_bounds__(256) void pack_all(
    const float* __restrict__ Wv, const float* __restrict__ Ws,
    const float* __restrict__ Wa, const float* __restrict__ Wo,
    __hip_bfloat16* __restrict__ wv_p, __hip_bfloat16* __restrict__ wsa_p,
    __hip_bfloat16* __restrict__ wo_p) {
  const int b = blockIdx.x, t = threadIdx.x;
  if (b < 32)       pack_one(Wv, Wv, 256, 256, wv_p,  b * 256 + t);
  else if (b < 80)  pack_one(Ws, Wa, 256, 384, wsa_p, (b - 32) * 256 + t);
  else              pack_one(Wo, Wo, 256, 256, wo_p,  (b - 80) * 256 + t);
}

// ---- A-stage: 64 rows x K=256 into fragment-ordered LDS ----
template<bool ABF16>
static __device__ __forceinline__ void stage_A(
    const void* __restrict__ Ain, int bm, int t, bf16x8* As) {
  const int r = t >> 2;
  const int row = bm + r;
  const int sm = r >> 4;
  const int lb = r & 15;
  const bool ok = row < M_;
  if (!ABF16) {
    const float* ap = (const float*)Ain + (size_t)row * 256 + (t & 3) * 64;
#pragma unroll
    for (int gi = 0; gi < 8; ++gi) {
      float4 u = make_float4(0.f,0.f,0.f,0.f), v = make_float4(0.f,0.f,0.f,0.f);
      if (ok) { u = *(const float4*)(ap + gi * 8); v = *(const float4*)(ap + gi * 8 + 4); }
      bf16x8 w;
      w[0]=(__bf16)u.x; w[1]=(__bf16)u.y; w[2]=(__bf16)u.z; w[3]=(__bf16)u.w;
      w[4]=(__bf16)v.x; w[5]=(__bf16)v.y; w[6]=(__bf16)v.z; w[7]=(__bf16)v.w;
      int k8 = (t & 3) * 8 + gi;
      As[((k8 >> 2) * 4 + sm) * 64 + lb + ((k8 & 3) << 4)] = w;
    }
  } else {
    const __hip_bfloat16* ap = (const __hip_bfloat16*)Ain + (size_t)row * 256 + (t & 3) * 64;
#pragma unroll
    for (int gi = 0; gi < 8; ++gi) {
      bf16x8 w = {};
      if (ok) w = *(const bf16x8*)(ap + gi * 8);
      int k8 = (t & 3) * 8 + gi;
      As[((k8 >> 2) * 4 + sm) * 64 + lb + ((k8 & 3) << 4)] = w;
    }
  }
}

// ---- fused value+params GEMM ----
// grid (416, 5): y<2 -> value slab y (N=256); y>=2 -> params slab y-2 (N=384).
// B fragments read directly from global (L2-hot). Epilogue via Cs transpose.
#define CSTR 68

__global__ __launch_bounds__(256) void gemm_qv(
    const float* __restrict__ inpf, const float* __restrict__ query,
    const bf16x8* __restrict__ wv_p, const bf16x8* __restrict__ wsa_p,
    const float* __restrict__ bv, const float* __restrict__ bs,
    const float* __restrict__ ba,
    __hip_bfloat16* __restrict__ value, float* __restrict__ params) {
  __shared__ bf16x8 As[8 * 4 * 64];     // 32 KB
  __shared__ float  Cs[64 * CSTR];      // 17.4 KB

  const int t = threadIdx.x;
  const int bm = blockIdx.x * 64;
  const int lane = t & 63, wid = t >> 6;
  const int wm = wid >> 1, wn = wid & 1;
  const int y = blockIdx.y;
  const bool isv = (y < 2);
  const int slab = isv ? y : y - 2;
  const bf16x8* Bp = isv ? wv_p : wsa_p;

  stage_A<false>(isv ? (const void*)inpf : (const void*)query, bm, t, As);
  __syncthreads();

  for (int nb = 0; nb < 2; ++nb) {
    const int colbase = slab * 128 + nb * 64;
    const bf16x8* bpn = Bp + (size_t)(colbase >> 6) * 2048;

    f32x4 acc[2][2] = {};
#pragma unroll
    for (int kt = 0; kt < 8; ++kt) {
      bf16x8 a0 = As[(kt * 4 + wm * 2 + 0) * 64 + lane];
      bf16x8 a1 = As[(kt * 4 + wm * 2 + 1) * 64 + lane];
      bf16x8 q0 = bpn[(kt * 4 + wn * 2 + 0) * 64 + lane];
      bf16x8 q1 = bpn[(kt * 4 + wn * 2 + 1) * 64 + lane];
      acc[0][0] = mfma16(a0, q0, acc[0][0]);
      acc[0][1] = mfma16(a0, q1, acc[0][1]);
      acc[1][0] = mfma16(a1, q0, acc[1][0]);
      acc[1][1] = mfma16(a1, q1, acc[1][1]);
    }

    // acc -> Cs
#pragma unroll
    for (int m = 0; m < 2; ++m)
#pragma unroll
      for (int n = 0; n < 2; ++n)
#pragma unroll
        for (int rg = 0; rg < 4; ++rg)
          Cs[(wm * 32 + m * 16 + (lane >> 4) * 4 + rg) * CSTR + wn * 32 + n * 16 + (lane & 15)] = acc[m][n][rg];
    __syncthreads();

    // coalesced store: thread t -> local row t>>2, 16 cols (t&3)*16
    {
      const int r = t >> 2;
      const int row = bm + r;
      const int c0l = (t & 3) * 16;
      const int c0 = colbase + c0l;
      float vv[16];
      *(float4*)&vv[0]  = *(float4*)&Cs[r * CSTR + c0l + 0];
      *(float4*)&vv[4]  = *(float4*)&Cs[r * CSTR + c0l + 4];
      *(float4*)&vv[8]  = *(float4*)&Cs[r * CSTR + c0l + 8];
      *(float4*)&vv[12] = *(float4*)&Cs[r * CSTR + c0l + 12];
      const float* bias = isv ? (bv + c0) : (c0 < 256 ? bs + c0 : ba + (c0 - 256));
#pragma unroll
      for (int j = 0; j < 16; ++j) vv[j] += bias[j];
      if (row < M_) {
        if (isv) {
          const int bb = row >= NK;
          const int key = row - bb * NK;
          const int head = c0 >> 5, c32 = c0 & 31;
          __hip_bfloat16* dst = value + (((size_t)(bb * 8 + head)) * NK + key) * 32 + c32;
          bf16x8 o0, o1;
#pragma unroll
          for (int j = 0; j < 8; ++j) { o0[j] = (__bf16)vv[j]; o1[j] = (__bf16)vv[8 + j]; }
          *(bf16x8*)(dst + 0) = o0;
          *(bf16x8*)(dst + 8) = o1;
        } else {
          float* dst = params + (size_t)row * 384 + c0;
          *(float4*)(dst + 0)  = *(float4*)&vv[0];
          *(float4*)(dst + 4)  = *(float4*)&vv[4];
          *(float4*)(dst + 8)  = *(float4*)&vv[8];
          *(float4*)(dst + 12) = *(float4*)&vv[12];
        }
      }
    }
    if (nb == 0) __syncthreads();
  }
}

// ---- out GEMM: out[M][256] = acc_bf16 @ wo_p + bo ; grid (416, 2) ----
__global__ __launch_bounds__(256) void gemm_out(
    const __hip_bfloat16* __restrict__ accin, const bf16x8* __restrict__ wo_p,
    const float* __restrict__ bo, float* __restrict__ out) {
  __shared__ bf16x8 As[8 * 4 * 64];
  __shared__ float  Cs[64 * CSTR];

  const int t = threadIdx.x;
  const int bm = blockIdx.x * 64;
  const int lane = t & 63, wid = t >> 6;
  const int wm = wid >> 1, wn = wid & 1;
  const int slab = blockIdx.y;

  stage_A<true>(accin, bm, t, As);
  __syncthreads();

  for (int nb = 0; nb < 2; ++nb) {
    const int colbase = slab * 128 + nb * 64;
    const bf16x8* bpn = wo_p + (size_t)(colbase >> 6) * 2048;

    f32x4 acc[2][2] = {};
#pragma unroll
    for (int kt = 0; kt < 8; ++kt) {
      bf16x8 a0 = As[(kt * 4 + wm * 2 + 0) * 64 + lane];
      bf16x8 a1 = As[(kt * 4 + wm * 2 + 1) * 64 + lane];
      bf16x8 q0 = bpn[(kt * 4 + wn * 2 + 0) * 64 + lane];
      bf16x8 q1 = bpn[(kt * 4 + wn * 2 + 1) * 64 + lane];
      acc[0][0] = mfma16(a0, q0, acc[0][0]);
      acc[0][1] = mfma16(a0, q1, acc[0][1]);
      acc[1][0] = mfma16(a1, q0, acc[1][0]);
      acc[1][1] = mfma16(a1, q1, acc[1][1]);
    }

#pragma unroll
    for (int m = 0; m < 2; ++m)
#pragma unroll
      for (int n = 0; n < 2; ++n)
#pragma unroll
        for (int rg = 0; rg < 4; ++rg)
          Cs[(wm * 32 + m * 16 + (lane >> 4) * 4 + rg) * CSTR + wn * 32 + n * 16 + (lane & 15)] = acc[m][n][rg];
    __syncthreads();

    {
      const int r = t >> 2;
      const int row = bm + r;
      const int c0l = (t & 3) * 16;
      const int c0 = colbase + c0l;
      float vv[16];
      *(float4*)&vv[0]  = *(float4*)&Cs[r * CSTR + c0l + 0];
      *(float4*)&vv[4]  = *(float4*)&Cs[r * CSTR + c0l + 4];
      *(float4*)&vv[8]  = *(float4*)&Cs[r * CSTR + c0l + 8];
      *(float4*)&vv[12] = *(float4*)&Cs[r * CSTR + c0l + 12];
#pragma unroll
      for (int j = 0; j < 16; ++j) vv[j] += bo[c0 + j];
      if (row < M_) {
        float* dst = out + (size_t)row * 256 + c0;
        *(float4*)(dst + 0)  = *(float4*)&vv[0];
        *(float4*)(dst + 4)  = *(float4*)&vv[4];
        *(float4*)(dst + 8)  = *(float4*)&vv[8];
        *(float4*)(dst + 12) = *(float4*)&vv[12];
      }
    }
    if (nb == 0) __syncthreads();
  }
}

// ---- sampler: softmax + bilinear combos + bf16 gather (head-major value) ----
// combo entry u32 = (bf16(weight)<<16) | key_idx ; region stride CS=65 words.
#define CS 65

__global__ __launch_bounds__(256) void sampler(
    const float* __restrict__ refp, const float* __restrict__ params,
    const __hip_bfloat16* __restrict__ value, __hip_bfloat16* __restrict__ acc_out) {
  __shared__ unsigned int combo[64 * CS];  // 16.6 KB

  const int t = threadIdx.x;
  const int q0 = blockIdx.x * 16;
  const int bb = blockIdx.y;

  const int cqi = t >> 5;          // build: query 0..7
  const int chh = (t >> 2) & 7;    // build: head
  const int cl  = t & 3;           // build: level

  const int lane = t & 63;
  const int wid  = t >> 6;
  const int q2   = lane >> 5;
  const int gh   = (lane >> 2) & 7;
  const int gs   = lane & 3;
  // uniform base + 32-bit per-lane voffset (8*NK*64B = 6.8 MB fits u32)
  const char* vb = (const char*)value;
  const unsigned int voff0 = (unsigned int)(((bb * 8 + gh) * NK) * 64 + gs * 16);

  const float DIMF[4]  = {100.f, 50.f, 25.f, 13.f};
  const int   LSTART[4] = {0, 10000, 12500, 13125};
  const float dimf  = DIMF[cl];
  const int   Wd    = (int)dimf;
  const int   lbase = LSTART[cl];

  for (int qc = 0; qc < 16; qc += 8) {
    __syncthreads();
    // ---- build: one thread per (q, head, level) ----
    {
      const int q = q0 + qc + cqi;
      const bool valid = q < NQ;
      const size_t row = (size_t)bb * NQ + (valid ? q : 0);
      const float* pr = params + row * 384;
      const float* lg = pr + 256 + chh * 16;
      float m = lg[0];
#pragma unroll
      for (int j = 1; j < 16; ++j) m = fmaxf(m, lg[j]);
      float s = 0.f;
#pragma unroll
      for (int j = 0; j < 16; ++j) s += __expf(lg[j] - m);
      const float inv = valid ? 1.f / s : 0.f;

      const float rx = refp[(row * 4 + cl) * 2 + 0];
      const float ry = refp[(row * 4 + cl) * 2 + 1];
      const float* of = pr + chh * 32 + cl * 8;
      unsigned int* cb = &combo[(cqi * 8 + chh) * CS + cl * 16];

#pragma unroll
      for (int p = 0; p < 4; ++p) {
        const float wa = __expf(lg[cl * 4 + p] - m) * inv;
        const float x = rx * dimf + of[p * 2 + 0] - 0.5f;
        const float y = ry * dimf + of[p * 2 + 1] - 0.5f;
        const float xf = floorf(x), yf = floorf(y);
        const float dx = x - xf, dy = y - yf;
        const int x0 = (int)xf, y0 = (int)yf;
        float w00 = (1.f - dx) * (1.f - dy) * wa;
        float w10 = dx * (1.f - dy) * wa;
        float w01 = (1.f - dx) * dy * wa;
        float w11 = dx * dy * wa;
        int i0, i1, i2, i3, xi, yi;
        xi = x0;     yi = y0;
        if (xi >= 0 && xi < Wd && yi >= 0 && yi < Wd) i0 = lbase + yi * Wd + xi; else { i0 = 0; w00 = 0.f; }
        xi = x0 + 1; yi = y0;
        if (xi >= 0 && xi < Wd && yi >= 0 && yi < Wd) i1 = lbase + yi * Wd + xi; else { i1 = 0; w10 = 0.f; }
        xi = x0;     yi = y0 + 1;
        if (xi >= 0 && xi < Wd && yi >= 0 && yi < Wd) i2 = lbase + yi * Wd + xi; else { i2 = 0; w01 = 0.f; }
        xi = x0 + 1; yi = y0 + 1;
        if (xi >= 0 && xi < Wd && yi >= 0 && yi < Wd) i3 = lbase + yi * Wd + xi; else { i3 = 0; w11 = 0.f; }
        // pack: round weight to bf16 (approx-RNE via +0x8000), idx in low 16
        cb[p * 4 + 0] = ((__float_as_uint(w00) + 0x8000u) & 0xffff0000u) | (unsigned)i0;
        cb[p * 4 + 1] = ((__float_as_uint(w10) + 0x8000u) & 0xffff0000u) | (unsigned)i1;
        cb[p * 4 + 2] = ((__float_as_uint(w01) + 0x8000u) & 0xffff0000u) | (unsigned)i2;
        cb[p * 4 + 3] = ((__float_as_uint(w11) + 0x8000u) & 0xffff0000u) | (unsigned)i3;
      }
    }
    __syncthreads();

    // ---- gather: wave wid covers queries {2*wid, 2*wid+1} of the chunk ----
    {
      const int qw = wid * 2 + q2;
      const int q = q0 + qc + qw;
      const unsigned int* cb = &combo[(qw * 8 + gh) * CS];
      float a0=0.f,a1=0.f,a2=0.f,a3=0.f,a4=0.f,a5=0.f,a6=0.f,a7=0.f;
#pragma unroll 8
      for (int e = 0; e < 64; ++e) {
        const unsigned int u = cb[e];
        const float w = __uint_as_float(u & 0xffff0000u);
        const unsigned int voff = voff0 + ((u & 0xffffu) << 6);
        const uint4 v = *(const uint4*)(vb + (size_t)voff);
        a0 += w * __uint_as_float(v.x << 16);
        a1 += w * __uint_as_float(v.x & 0xffff0000u);
        a2 += w * __uint_as_float(v.y << 16);
        a3 += w * __uint_as_float(v.y & 0xffff0000u);
        a4 += w * __uint_as_float(v.z << 16);
        a5 += w * __uint_as_float(v.z & 0xffff0000u);
        a6 += w * __uint_as_float(v.w << 16);
        a7 += w * __uint_as_float(v.w & 0xffff0000u);
      }
      if (q < NQ) {
        bf16x8 o;
        o[0]=(__bf16)a0; o[1]=(__bf16)a1; o[2]=(__bf16)a2; o[3]=(__bf16)a3;
        o[4]=(__bf16)a4; o[5]=(__bf16)a5; o[6]=(__bf16)a6; o[7]=(__bf16)a7;
        *(bf16x8*)((char*)acc_out + (((size_t)bb * NQ + q) * 256 + gh * 32 + gs * 8) * 2) = o;
      }
    }
  }
}

extern "C" void kernel_launch(void* const* d_in, const int* in_sizes, int n_in,
                              void* d_out, int out_size, void* d_ws, size_t ws_size,
                              hipStream_t stream) {
  const float* query = (const float*)d_in[0];
  const float* refp  = (const float*)d_in[1];
  const float* inpf  = (const float*)d_in[2];
  const float* Wv    = (const float*)d_in[3];
  const float* bv    = (const float*)d_in[4];
  const float* Ws    = (const float*)d_in[5];
  const float* bs    = (const float*)d_in[6];
  const float* Wa    = (const float*)d_in[7];
  const float* ba    = (const float*)d_in[8];
  const float* Wo    = (const float*)d_in[9];
  const float* bo    = (const float*)d_in[10];
  float* out = (float*)d_out;

  char* w = (char*)d_ws;
  __hip_bfloat16* value  = (__hip_bfloat16*)w;            w += (size_t)M_ * 256 * 2;  // head-major
  __hip_bfloat16* acc    = (__hip_bfloat16*)w;            w += (size_t)M_ * 256 * 2;
  float*          params = (float*)w;                     w += (size_t)M_ * 384 * 4;
  __hip_bfloat16* wv_p   = (__hip_bfloat16*)w;            w += 256 * 256 * 2;
  __hip_bfloat16* wsa_p  = (__hip_bfloat16*)w;            w += 256 * 384 * 2;
  __hip_bfloat16* wo_p   = (__hip_bfloat16*)w;

  pack_all<<<112, 256, 0, stream>>>(Wv, Ws, Wa, Wo, wv_p, wsa_p, wo_p);

  const int gx = (M_ + 63) / 64;  // 416
  gemm_qv<<<dim3(gx, 5), 256, 0, stream>>>(inpf, query, (const bf16x8*)wv_p,
                                           (const bf16x8*)wsa_p, bv, bs, ba,
                                           value, params);

  dim3 sgrid((NQ + 15) / 16, B_);
  sampler<<<sgrid, 256, 0, stream>>>(refp, params, value, acc);

  gemm_out<<<dim3(gx, 2), 256, 0, stream>>>(acc, (const bf16x8*)wo_p, bo, out);
}

// Round 6
// 141.152 us; speedup vs baseline: 1.1321x; 1.1321x over previous
//
#include <hip/hip_runtime.h>
#include <hip/hip_bf16.h>
#include <math.h>

#define B_  2
#define NQ  13294
#define NK  13294
#define M_  (B_ * NK)   // 26588
#define MT  32          // GEMM M-tile rows
#define GX  ((M_ + MT - 1) / MT)  // 831

typedef __bf16 bf16x8 __attribute__((ext_vector_type(8)));
typedef float f32x4 __attribute__((ext_vector_type(4)));

static __device__ __forceinline__ f32x4 mfma16(bf16x8 a, bf16x8 b, f32x4 c) {
  return __builtin_amdgcn_mfma_f32_16x16x32_bf16(a, b, c, 0, 0, 0);
}

// ---- pack weights f32 [K=256][N] -> bf16 MFMA B-fragment layout ----
// bf16x8 slot g: lane=g&63, n_sub=(g>>6)&3, kt=(g>>8)&7, bn=g>>11
// n = bn*64 + n_sub*16 + (lane&15),  k = kt*32 + (lane>>4)*8 + j
static __device__ __forceinline__ void pack_one(
    const float* __restrict__ W1, const float* __restrict__ W2,
    int N1, int Ntot, __hip_bfloat16* __restrict__ out, int g) {
  int lane = g & 63;
  int n_sub = (g >> 6) & 3;
  int kt = (g >> 8) & 7;
  int bn = g >> 11;
  int n = bn * 64 + n_sub * 16 + (lane & 15);
  int k0 = kt * 32 + (lane >> 4) * 8;
  const float* src; int nn, Ns;
  if (n < N1) { src = W1; nn = n; Ns = N1; }
  else        { src = W2; nn = n - N1; Ns = Ntot - N1; }
  bf16x8 v;
#pragma unroll
  for (int j = 0; j < 8; ++j) v[j] = (__bf16)src[(size_t)(k0 + j) * Ns + nn];
  *(bf16x8*)(out + (size_t)g * 8) = v;
}

__global__ __launch_bounds__(256) void pack_all(
    const float* __restrict__ Wv, const float* __restrict__ Ws,
    const float* __restrict__ Wa, const float* __restrict__ Wo,
    __hip_bfloat16* __restrict__ wv_p, __hip_bfloat16* __restrict__ wsa_p,
    __hip_bfloat16* __restrict__ wo_p) {
  const int b = blockIdx.x, t = threadIdx.x;
  if (b < 32)       pack_one(Wv, Wv, 256, 256, wv_p,  b * 256 + t);
  else if (b < 80)  pack_one(Ws, Wa, 256, 384, wsa_p, (b - 32) * 256 + t);
  else              pack_one(Wo, Wo, 256, 256, wo_p,  (b - 80) * 256 + t);
}

// ---- unified 32-row-tile GEMM: C[M][N] = A[M][256] @ Wpack + bias ----
// mode 0: A=inpf(f32)  B=wv_p  N=256 out=value(bf16, row-major [row][256])
// mode 1: A=query(f32) B=wsa_p N=384 out=params(f32)
// mode 2: A=acc(bf16)  B=wo_p  N=256 out=out(f32)
// 128 threads (2 waves); block stages A once, waves alternate 64-col blocks;
// epilogue via wave-private Cs transpose -> coalesced row stores. No barriers
// in the nb loop.
#define CSTR 68

__global__ __launch_bounds__(128) void gemm_mt(
    const float* __restrict__ inpf, const float* __restrict__ query,
    const __hip_bfloat16* __restrict__ accin,
    const bf16x8* __restrict__ wv_p, const bf16x8* __restrict__ wsa_p,
    const bf16x8* __restrict__ wo_p,
    const float* __restrict__ bv, const float* __restrict__ bs,
    const float* __restrict__ ba, const float* __restrict__ bo,
    __hip_bfloat16* __restrict__ value, float* __restrict__ params,
    float* __restrict__ outp, int mode_base) {
  __shared__ bf16x8 As[8 * 2 * 64];        // 16 KB
  __shared__ float  Cs[2 * MT * CSTR];     // 17.4 KB

  const int t = threadIdx.x;
  const int bm = blockIdx.x * MT;
  const int lane = t & 63, wid = t >> 6;
  const int mode = mode_base + blockIdx.y;

  // ---- stage A (32 rows x K=256) in fragment order ----
  {
    const int r = t >> 2;        // 0..31
    const int row = bm + r;
    const int sm = r >> 4;
    const int lb = r & 15;
    const bool ok = row < M_;
    if (mode != 2) {
      const float* Af = (mode == 0) ? inpf : query;
      const float* ap = Af + (size_t)row * 256 + (t & 3) * 64;
#pragma unroll
      for (int gi = 0; gi < 8; ++gi) {
        float4 u = make_float4(0.f,0.f,0.f,0.f), v = make_float4(0.f,0.f,0.f,0.f);
        if (ok) { u = *(const float4*)(ap + gi * 8); v = *(const float4*)(ap + gi * 8 + 4); }
        bf16x8 w;
        w[0]=(__bf16)u.x; w[1]=(__bf16)u.y; w[2]=(__bf16)u.z; w[3]=(__bf16)u.w;
        w[4]=(__bf16)v.x; w[5]=(__bf16)v.y; w[6]=(__bf16)v.z; w[7]=(__bf16)v.w;
        int k8 = (t & 3) * 8 + gi;
        As[((k8 >> 2) * 2 + sm) * 64 + lb + ((k8 & 3) << 4)] = w;
      }
    } else {
      const __hip_bfloat16* ap = accin + (size_t)row * 256 + (t & 3) * 64;
#pragma unroll
      for (int gi = 0; gi < 8; ++gi) {
        bf16x8 w = {};
        if (ok) w = *(const bf16x8*)(ap + gi * 8);
        int k8 = (t & 3) * 8 + gi;
        As[((k8 >> 2) * 2 + sm) * 64 + lb + ((k8 & 3) << 4)] = w;
      }
    }
  }
  __syncthreads();

  const bf16x8* Bp = (mode == 0) ? wv_p : (mode == 1) ? wsa_p : wo_p;
  const int NB = (mode == 1) ? 6 : 4;
  float* Cw = &Cs[wid * MT * CSTR];

  for (int nb = wid; nb < NB; nb += 2) {
    const int colbase = nb * 64;
    const bf16x8* bpn = Bp + (size_t)nb * 2048;

    f32x4 acc[2][4] = {};
#pragma unroll
    for (int kt = 0; kt < 8; ++kt) {
      bf16x8 a0 = As[(kt * 2 + 0) * 64 + lane];
      bf16x8 a1 = As[(kt * 2 + 1) * 64 + lane];
#pragma unroll
      for (int n = 0; n < 4; ++n) {
        bf16x8 b = bpn[(kt * 4 + n) * 64 + lane];
        acc[0][n] = mfma16(a0, b, acc[0][n]);
        acc[1][n] = mfma16(a1, b, acc[1][n]);
      }
    }

    // fragment -> wave-private Cs (no block barrier needed)
#pragma unroll
    for (int m = 0; m < 2; ++m)
#pragma unroll
      for (int n = 0; n < 4; ++n)
#pragma unroll
        for (int rg = 0; rg < 4; ++rg)
          Cw[(m * 16 + (lane >> 4) * 4 + rg) * CSTR + n * 16 + (lane & 15)] = acc[m][n][rg];

    if (mode == 0) {
      // bf16 value, row-major: lane covers 8 cols, 8 rows/pass, 4 passes
#pragma unroll
      for (int p = 0; p < 4; ++p) {
        const int r = (lane >> 3) + p * 8;
        const int c = (lane & 7) * 8;
        const int row = bm + r;
        float4 u = *(float4*)&Cw[r * CSTR + c];
        float4 v = *(float4*)&Cw[r * CSTR + c + 4];
        const float* bias = bv + colbase + c;
        bf16x8 o;
        o[0]=(__bf16)(u.x+bias[0]); o[1]=(__bf16)(u.y+bias[1]);
        o[2]=(__bf16)(u.z+bias[2]); o[3]=(__bf16)(u.w+bias[3]);
        o[4]=(__bf16)(v.x+bias[4]); o[5]=(__bf16)(v.y+bias[5]);
        o[6]=(__bf16)(v.z+bias[6]); o[7]=(__bf16)(v.w+bias[7]);
        if (row < M_)
          *(bf16x8*)(value + (size_t)row * 256 + colbase + c) = o;
      }
    } else {
      // f32 out: lane covers 4 cols (float4), 16 lanes/row, 4 rows/pass, 8 passes
      float* Of = (mode == 1) ? params : outp;
      const int stride = (mode == 1) ? 384 : 256;
#pragma unroll
      for (int p = 0; p < 8; ++p) {
        const int r = (lane >> 4) + p * 4;
        const int c = (lane & 15) * 4;
        const int row = bm + r;
        const int col = colbase + c;
        float4 u = *(float4*)&Cw[r * CSTR + c];
        const float* bias;
        if (mode == 1) bias = (col < 256) ? (bs + col) : (ba + col - 256);
        else           bias = bo + col;
        u.x += bias[0]; u.y += bias[1]; u.z += bias[2]; u.w += bias[3];
        if (row < M_)
          *(float4*)(Of + (size_t)row * stride + col) = u;
      }
    }
  }
}

// ---- sampler: softmax + bilinear combos + bf16 gather (key-major value) ----
// combo entry u32 = (bf16(weight)<<16) | key_idx ; region stride CS=65 words.
#define CS 65

__global__ __launch_bounds__(256) void sampler(
    const float* __restrict__ refp, const float* __restrict__ params,
    const __hip_bfloat16* __restrict__ value, __hip_bfloat16* __restrict__ acc_out) {
  __shared__ unsigned int combo[64 * CS];  // 16.6 KB

  const int t = threadIdx.x;
  const int q0 = blockIdx.x * 16;
  const int bb = blockIdx.y;

  const int cqi = t >> 5;          // build: query 0..7
  const int chh = (t >> 2) & 7;    // build: head
  const int cl  = t & 3;           // build: level

  const int lane = t & 63;
  const int wid  = t >> 6;
  const int q2   = lane >> 5;
  const int gh   = (lane >> 2) & 7;
  const int gs   = lane & 3;
  // key-major: 512 B contiguous per key; uniform base + u32 voffset
  const char* vb = (const char*)value;
  const unsigned int voff0 = (unsigned int)bb * (NK * 512u) + (unsigned)(gh * 64 + gs * 16);

  const float DIMF[4]  = {100.f, 50.f, 25.f, 13.f};
  const int   LSTART[4] = {0, 10000, 12500, 13125};
  const float dimf  = DIMF[cl];
  const int   Wd    = (int)dimf;
  const int   lbase = LSTART[cl];

  for (int qc = 0; qc < 16; qc += 8) {
    __syncthreads();
    // ---- build: one thread per (q, head, level) ----
    {
      const int q = q0 + qc + cqi;
      const bool valid = q < NQ;
      const size_t row = (size_t)bb * NQ + (valid ? q : 0);
      const float* pr = params + row * 384;
      const float* lg = pr + 256 + chh * 16;
      float m = lg[0];
#pragma unroll
      for (int j = 1; j < 16; ++j) m = fmaxf(m, lg[j]);
      float s = 0.f;
#pragma unroll
      for (int j = 0; j < 16; ++j) s += __expf(lg[j] - m);
      const float inv = valid ? 1.f / s : 0.f;

      const float rx = refp[(row * 4 + cl) * 2 + 0];
      const float ry = refp[(row * 4 + cl) * 2 + 1];
      const float* of = pr + chh * 32 + cl * 8;
      unsigned int* cb = &combo[(cqi * 8 + chh) * CS + cl * 16];

#pragma unroll
      for (int p = 0; p < 4; ++p) {
        const float wa = __expf(lg[cl * 4 + p] - m) * inv;
        const float x = rx * dimf + of[p * 2 + 0] - 0.5f;
        const float y = ry * dimf + of[p * 2 + 1] - 0.5f;
        const float xf = floorf(x), yf = floorf(y);
        const float dx = x - xf, dy = y - yf;
        const int x0 = (int)xf, y0 = (int)yf;
        float w00 = (1.f - dx) * (1.f - dy) * wa;
        float w10 = dx * (1.f - dy) * wa;
        float w01 = (1.f - dx) * dy * wa;
        float w11 = dx * dy * wa;
        int i0, i1, i2, i3, xi, yi;
        xi = x0;     yi = y0;
        if (xi >= 0 && xi < Wd && yi >= 0 && yi < Wd) i0 = lbase + yi * Wd + xi; else { i0 = 0; w00 = 0.f; }
        xi = x0 + 1; yi = y0;
        if (xi >= 0 && xi < Wd && yi >= 0 && yi < Wd) i1 = lbase + yi * Wd + xi; else { i1 = 0; w10 = 0.f; }
        xi = x0;     yi = y0 + 1;
        if (xi >= 0 && xi < Wd && yi >= 0 && yi < Wd) i2 = lbase + yi * Wd + xi; else { i2 = 0; w01 = 0.f; }
        xi = x0 + 1; yi = y0 + 1;
        if (xi >= 0 && xi < Wd && yi >= 0 && yi < Wd) i3 = lbase + yi * Wd + xi; else { i3 = 0; w11 = 0.f; }
        cb[p * 4 + 0] = ((__float_as_uint(w00) + 0x8000u) & 0xffff0000u) | (unsigned)i0;
        cb[p * 4 + 1] = ((__float_as_uint(w10) + 0x8000u) & 0xffff0000u) | (unsigned)i1;
        cb[p * 4 + 2] = ((__float_as_uint(w01) + 0x8000u) & 0xffff0000u) | (unsigned)i2;
        cb[p * 4 + 3] = ((__float_as_uint(w11) + 0x8000u) & 0xffff0000u) | (unsigned)i3;
      }
    }
    __syncthreads();

    // ---- gather: wave wid covers queries {2*wid, 2*wid+1} of the chunk ----
    {
      const int qw = wid * 2 + q2;
      const int q = q0 + qc + qw;
      const unsigned int* cb = &combo[(qw * 8 + gh) * CS];
      float a0=0.f,a1=0.f,a2=0.f,a3=0.f,a4=0.f,a5=0.f,a6=0.f,a7=0.f;
#pragma unroll 16
      for (int e = 0; e < 64; ++e) {
        const unsigned int u = cb[e];
        const float w = __uint_as_float(u & 0xffff0000u);
        const unsigned int voff = voff0 + ((u & 0xffffu) << 9);
        const uint4 v = *(const uint4*)(vb + (size_t)voff);
        a0 += w * __uint_as_float(v.x << 16);
        a1 += w * __uint_as_float(v.x & 0xffff0000u);
        a2 += w * __uint_as_float(v.y << 16);
        a3 += w * __uint_as_float(v.y & 0xffff0000u);
        a4 += w * __uint_as_float(v.z << 16);
        a5 += w * __uint_as_float(v.z & 0xffff0000u);
        a6 += w * __uint_as_float(v.w << 16);
        a7 += w * __uint_as_float(v.w & 0xffff0000u);
      }
      if (q < NQ) {
        bf16x8 o;
        o[0]=(__bf16)a0; o[1]=(__bf16)a1; o[2]=(__bf16)a2; o[3]=(__bf16)a3;
        o[4]=(__bf16)a4; o[5]=(__bf16)a5; o[6]=(__bf16)a6; o[7]=(__bf16)a7;
        *(bf16x8*)((char*)acc_out + (((size_t)bb * NQ + q) * 256 + gh * 32 + gs * 8) * 2) = o;
      }
    }
  }
}

extern "C" void kernel_launch(void* const* d_in, const int* in_sizes, int n_in,
                              void* d_out, int out_size, void* d_ws, size_t ws_size,
                              hipStream_t stream) {
  const float* query = (const float*)d_in[0];
  const float* refp  = (const float*)d_in[1];
  const float* inpf  = (const float*)d_in[2];
  const float* Wv    = (const float*)d_in[3];
  const float* bv    = (const float*)d_in[4];
  const float* Ws    = (const float*)d_in[5];
  const float* bs    = (const float*)d_in[6];
  const float* Wa    = (const float*)d_in[7];
  const float* ba    = (const float*)d_in[8];
  const float* Wo    = (const float*)d_in[9];
  const float* bo    = (const float*)d_in[10];
  float* out = (float*)d_out;

  char* w = (char*)d_ws;
  __hip_bfloat16* value  = (__hip_bfloat16*)w;            w += (size_t)M_ * 256 * 2;  // key-major
  __hip_bfloat16* acc    = (__hip_bfloat16*)w;            w += (size_t)M_ * 256 * 2;
  float*          params = (float*)w;                     w += (size_t)M_ * 384 * 4;
  __hip_bfloat16* wv_p   = (__hip_bfloat16*)w;            w += 256 * 256 * 2;
  __hip_bfloat16* wsa_p  = (__hip_bfloat16*)w;            w += 256 * 384 * 2;
  __hip_bfloat16* wo_p   = (__hip_bfloat16*)w;

  pack_all<<<112, 256, 0, stream>>>(Wv, Ws, Wa, Wo, wv_p, wsa_p, wo_p);

  gemm_mt<<<dim3(GX, 2), 128, 0, stream>>>(
      inpf, query, acc, (const bf16x8*)wv_p, (const bf16x8*)wsa_p,
      (const bf16x8*)wo_p, bv, bs, ba, bo, value, params, out, 0);

  dim3 sgrid((NQ + 15) / 16, B_);
  sampler<<<sgrid, 256, 0, stream>>>(refp, params, value, acc);

  gemm_mt<<<dim3(GX, 1), 128, 0, stream>>>(
      inpf, query, acc, (const bf16x8*)wv_p, (const bf16x8*)wsa_p,
      (const bf16x8*)wo_p, bv, bs, ba, bo, value, params, out, 2);
}